// Round 9
// baseline (338.380 us; speedup 1.0000x reference)
//
#include <hip/hip_runtime.h>
#include <math.h>

// out[n,o] = exp(A)*cos(B)
//   A = sum_i ln(R)*Wr - K*Wi ;  B = sum_i ln(R)*Wi + K*Wr
//   R = 1 + g*(|x|-1),  K = pi*(x<0)*g,  g = clip(G,0,1)
// n=8192, i=o=128.
//
// R19: DECISIVE ablation -- exec vs latency.
// Falsified so far: LDS-broadcast, weight-stream, log, LDS-reads, packing,
// instr-count 9->5, occupancy 16 vs 32 w/CU. R17's matrix left a hole: every
// variant kept exec+log plus >=1 memory stream. The ~450cy/wave-iter wall is
// either (E) VALU/issue slower than modeled or (L) latency-exposed on any
// remaining stream. Opposite fixes -> measure:
//   V4 R4: pure-exec (operands in regs, asm-opaqued per iter, no memory).
//          E => ~96us; L => ~35-55.
//   V5 R4: pure-mem+log (LDS + weights + fma/log, no acc; asm keeps live).
//          L => ~96us; E => ~35-50.
//   V7 R4: full V0 body FULLY UNROLLED (32x) -> tests loop/sched-window
//          overhead. V7 << 96 => ship full-unroll next round.
//   V0 R1: R18 verified kernel, LAST, correct output.
// Geometry all variants (== R17/R18): RPB=16, NT=512, 512 blocks, LB(512,4),
// 32KB LDS.

#define NROWS 8192
#define DIM   128
#define RPB   16
#define NT    512
#define PI_F  3.14159265358979323846f
#define LN2_F 0.69314718055994530942f

// prep: 64 blocks x 256. wq[i*128+o] = (ln2*wr, ln2*wi, g, unused)
//                        wb[i*128+o] = (-pi*g*wi, pi*g*wr)
__global__ __launch_bounds__(256) void prep(
    const float* __restrict__ Wr, const float* __restrict__ Wi,
    const float* __restrict__ G,
    float4* __restrict__ wq, float2* __restrict__ wb)
{
    int t = blockIdx.x * 256 + threadIdx.x;
    if (t < DIM * DIM) {
        float g  = fminf(fmaxf(G[t], 0.0f), 1.0f);
        float wr = Wr[t], wi = Wi[t];
        wq[t] = make_float4(LN2_F * wr, LN2_F * wi, g, 0.0f);
        wb[t] = make_float2(-PI_F * g * wi, PI_F * g * wr);
    }
}

// V: 0=full(R18)  4=pure-exec  5=pure-mem+log  7=full, fully unrolled
template <int V, int REP>
__global__ __launch_bounds__(NT, 4) void main_kernel(
    const float* __restrict__ x, const float4* __restrict__ wq,
    const float2* __restrict__ wb, float* __restrict__ out)
{
    __shared__ float sbuf[4 * RPB * DIM];
    float* am1p = sbuf;               // [DIM][RPB]
    float* sfp  = sbuf + DIM * RPB;   // [DIM][RPB]

    const int tid   = threadIdx.x;
    const int lane  = tid & 63;
    const int w     = tid >> 6;
    const int h     = w & 1;
    const int iq    = w >> 1;
    const int i0    = iq * 32;
    const int o     = h * 64 + lane;
    const int nbase = blockIdx.x * RPB;

    {   // Stage x tile (16 rows x 128 i): float4 coalesced.
        const float4* xb = (const float4*)(x + (size_t)nbase * DIM);
        float4 v = xb[tid];
        int e = tid * 4;
        int i = e & (DIM - 1), r = e >> 7;
        float vv[4] = {v.x, v.y, v.z, v.w};
#pragma unroll
        for (int k = 0; k < 4; ++k) {
            am1p[(i + k) * RPB + r] = fabsf(vv[k]) - 1.0f;
            sfp[(i + k) * RPB + r]  = (vv[k] < 0.0f) ? 1.0f : 0.0f;
        }
    }
    __syncthreads();

    float accA[RPB], accB[RPB];
#pragma unroll
    for (int r = 0; r < RPB; ++r) { accA[r] = 0.0f; accB[r] = 0.0f; }

    const float4* wqp = wq + (size_t)i0 * DIM + o;
    const float2* wbp = wb + (size_t)i0 * DIM + o;
    float4 wq0 = wqp[0], wq1 = wqp[DIM];
    float2 wb0 = wbp[0], wb1 = wbp[DIM];

    if constexpr (V == 4) {
        // ---- PURE EXEC: operands preloaded once, asm-opaqued per iter ----
        float av[RPB], sv[RPB];
        {
            const float4* a4 = (const float4*)(am1p + i0 * RPB);
            const float4* s4 = (const float4*)(sfp  + i0 * RPB);
#pragma unroll
            for (int b = 0; b < 4; ++b) {
                float4 a = a4[b], s = s4[b];
                av[4*b] = a.x; av[4*b+1] = a.y; av[4*b+2] = a.z; av[4*b+3] = a.w;
                sv[4*b] = s.x; sv[4*b+1] = s.y; sv[4*b+2] = s.z; sv[4*b+3] = s.w;
            }
        }
        const float g = wq0.z, wrl = wq0.x, wil = wq0.y;
        const float ngwi = wb0.x, pgwr = wb0.y;
#pragma unroll 1
        for (int rep = 0; rep < REP; ++rep) {
#pragma unroll 2
            for (int ii = 0; ii < 32; ++ii) {
#pragma unroll
                for (int r = 0; r < RPB; ++r) {
                    asm volatile("" : "+v"(av[r]), "+v"(sv[r]));  // defeat LICM
                    float t = fmaf(g, av[r], 1.0f);
                    float l = __log2f(t);
                    accA[r] = fmaf(l, wrl, fmaf(sv[r], ngwi, accA[r]));
                    accB[r] = fmaf(l, wil, fmaf(sv[r], pgwr, accB[r]));
                }
            }
        }
    } else if constexpr (V == 5) {
        // ---- PURE MEM+LOG: full load streams, no accumulation ----
#pragma unroll 1
        for (int rep = 0; rep < REP; ++rep) {
#pragma unroll 2
            for (int ii = 0; ii < 32; ++ii) {
                const int iw = (ii + rep) & 31;
                const int p2 = (iw + 2) & 31;
                float4 wqn = wqp[(size_t)p2 * DIM];
                float2 wbn = wbp[(size_t)p2 * DIM];
                const int i = i0 + iw;
                const float4* a4 = (const float4*)(am1p + i * RPB);
                const float4* s4 = (const float4*)(sfp  + i * RPB);
                const float g = wq0.z, wrl = wq0.x;
#pragma unroll
                for (int b = 0; b < 4; ++b) {
                    float4 a = a4[b], s = s4[b];
                    float t0 = fmaf(g, a.x, 1.0f), t1 = fmaf(g, a.y, 1.0f);
                    float t2 = fmaf(g, a.z, 1.0f), t3 = fmaf(g, a.w, 1.0f);
                    float l0 = __log2f(t0), l1 = __log2f(t1);
                    float l2 = __log2f(t2), l3 = __log2f(t3);
                    asm volatile("" :: "v"(l0), "v"(l1), "v"(l2), "v"(l3),
                                       "v"(s.x), "v"(s.y), "v"(s.z), "v"(s.w));
                }
                asm volatile("" :: "v"(wrl), "v"(wb0.x), "v"(wb0.y), "v"(wq0.y));
                wq0 = wq1; wq1 = wqn; wb0 = wb1; wb1 = wbn;
            }
        }
    } else {
        // ---- FULL LOOP (V0: unroll 2 == R18; V7: fully unrolled) ----
#pragma unroll 1
        for (int rep = 0; rep < REP; ++rep) {
#if 1
#pragma unroll (V == 7 ? 32 : 2)
#endif
            for (int ii = 0; ii < 32; ++ii) {
                const int iw = (ii + rep) & 31;
                const int p2 = (iw + 2) & 31;
                float4 wqn = wqp[(size_t)p2 * DIM];
                float2 wbn = wbp[(size_t)p2 * DIM];

                const int i = i0 + iw;
                const float4* a4 = (const float4*)(am1p + i * RPB);
                const float4* s4 = (const float4*)(sfp  + i * RPB);
                float4 aA = a4[0], aB = a4[1], aC = a4[2], aD = a4[3];
                float4 sA = s4[0], sB = s4[1], sC = s4[2], sD = s4[3];

                const float g    = wq0.z;
                const float wrl  = wq0.x, wil = wq0.y;
                const float ngwi = wb0.x, pgwr = wb0.y;

                const float av[16] = {aA.x, aA.y, aA.z, aA.w, aB.x, aB.y, aB.z, aB.w,
                                      aC.x, aC.y, aC.z, aC.w, aD.x, aD.y, aD.z, aD.w};
                const float sv[16] = {sA.x, sA.y, sA.z, sA.w, sB.x, sB.y, sB.z, sB.w,
                                      sC.x, sC.y, sC.z, sC.w, sD.x, sD.y, sD.z, sD.w};
#pragma unroll
                for (int r = 0; r < RPB; ++r) {
                    float t = fmaf(g, av[r], 1.0f);
                    float l = __log2f(t);
                    asm("" : "+v"(l));
                    accA[r] = fmaf(l, wrl, fmaf(sv[r], ngwi, accA[r]));
                    accB[r] = fmaf(l, wil, fmaf(sv[r], pgwr, accB[r]));
                }
                wq0 = wq1; wq1 = wqn;
                wb0 = wb1; wb1 = wbn;
            }
        }
    }

    // Epilogue: iq-reduce via the full 32 KB buffer, A then B.
    float* pP = sbuf;                        // [4][RPB][DIM]
    const int c4 = tid * 4;

    __syncthreads();
#pragma unroll
    for (int r = 0; r < RPB; ++r)
        pP[iq * (RPB * DIM) + r * DIM + o] = accA[r];
    __syncthreads();
    float4 A4 = make_float4(0.f, 0.f, 0.f, 0.f);
#pragma unroll
    for (int q2 = 0; q2 < 4; ++q2) {
        float4 t = *(const float4*)&pP[q2 * (RPB * DIM) + c4];
        A4.x += t.x; A4.y += t.y; A4.z += t.z; A4.w += t.w;
    }
    __syncthreads();
#pragma unroll
    for (int r = 0; r < RPB; ++r)
        pP[iq * (RPB * DIM) + r * DIM + o] = accB[r];
    __syncthreads();
    float4 B4 = make_float4(0.f, 0.f, 0.f, 0.f);
#pragma unroll
    for (int q2 = 0; q2 < 4; ++q2) {
        float4 t = *(const float4*)&pP[q2 * (RPB * DIM) + c4];
        B4.x += t.x; B4.y += t.y; B4.z += t.z; B4.w += t.w;
    }

    float4 res;
    res.x = __expf(A4.x) * __cosf(B4.x);
    res.y = __expf(A4.y) * __cosf(B4.y);
    res.z = __expf(A4.z) * __cosf(B4.z);
    res.w = __expf(A4.w) * __cosf(B4.w);
    ((float4*)(out + (size_t)nbase * DIM))[tid] = res;
}

// Fallback (no workspace): verified scalar LDS-plane kernel (RPB=8).
__global__ __launch_bounds__(NT, 4) void fb_kernel(
    const float* __restrict__ x,
    const float* __restrict__ Wr, const float* __restrict__ Wi,
    const float* __restrict__ G, float* __restrict__ out)
{
    __shared__ float sbuf[4 * 8 * DIM];
    float* am1p = sbuf;
    float* psp  = sbuf + DIM * 8;

    const int tid   = threadIdx.x;
    const int o     = tid & (DIM - 1);
    const int q     = tid >> 7;
    const int nbase = blockIdx.x * 8;

    {
        const float* xb = x + (size_t)nbase * DIM;
        float2 v = ((const float2*)xb)[tid];
        int e = tid * 2;
        int i = e & (DIM - 1), r = e >> 7;
        am1p[i * 8 + r]       = fabsf(v.x) - 1.0f;
        am1p[(i + 1) * 8 + r] = fabsf(v.y) - 1.0f;
        psp[i * 8 + r]        = (v.x < 0.0f) ? 1.0f : 0.0f;
        psp[(i + 1) * 8 + r]  = (v.y < 0.0f) ? 1.0f : 0.0f;
    }
    __syncthreads();

    float accA[8], accB[8];
#pragma unroll
    for (int r = 0; r < 8; ++r) { accA[r] = 0.0f; accB[r] = 0.0f; }

    const int ibase = q * 32;
#pragma unroll 2
    for (int ii = 0; ii < 32; ++ii) {
        const int i = ibase + ii;
        const int wi_idx = i * DIM + o;
        float g   = fminf(fmaxf(G[wi_idx], 0.0f), 1.0f);
        float wrl = LN2_F * Wr[wi_idx];
        float wil = LN2_F * Wi[wi_idx];
        const float ngwi = -PI_F * g * (wil * (1.0f / LN2_F));
        const float pgwr =  PI_F * g * (wrl * (1.0f / LN2_F));

        const float4* a4 = (const float4*)(am1p + i * 8);
        const float4* p4 = (const float4*)(psp  + i * 8);
        float4 a03 = a4[0], a47 = a4[1];
        float4 s03 = p4[0], s47 = p4[1];
        const float av[8] = {a03.x, a03.y, a03.z, a03.w, a47.x, a47.y, a47.z, a47.w};
        const float sv[8] = {s03.x, s03.y, s03.z, s03.w, s47.x, s47.y, s47.z, s47.w};

#pragma unroll
        for (int r = 0; r < 8; ++r) {
            float t = fmaf(g, av[r], 1.0f);
            float l = __log2f(t);
            asm("" : "+v"(l));
            accA[r] = fmaf(l, wrl, fmaf(sv[r], ngwi, accA[r]));
            accB[r] = fmaf(l, wil, fmaf(sv[r], pgwr, accB[r]));
        }
    }

    float* pP = sbuf;
    const int c = tid * 2;
    const int r = c >> 7, oo = c & (DIM - 1);

    __syncthreads();
#pragma unroll
    for (int p = 0; p < 8; ++p)
        pP[q * (8 * DIM) + p * DIM + o] = accA[p];
    __syncthreads();
    float2 A = make_float2(0.f, 0.f);
#pragma unroll
    for (int qq = 0; qq < 4; ++qq) {
        float2 t = *(const float2*)&pP[qq * (8 * DIM) + r * DIM + oo];
        A.x += t.x; A.y += t.y;
    }
    __syncthreads();
#pragma unroll
    for (int p = 0; p < 8; ++p)
        pP[q * (8 * DIM) + p * DIM + o] = accB[p];
    __syncthreads();
    float2 B = make_float2(0.f, 0.f);
#pragma unroll
    for (int qq = 0; qq < 4; ++qq) {
        float2 t = *(const float2*)&pP[qq * (8 * DIM) + r * DIM + oo];
        B.x += t.x; B.y += t.y;
    }

    float2 res;
    res.x = __expf(A.x) * __cosf(B.x);
    res.y = __expf(A.y) * __cosf(B.y);
    *(float2*)&out[(size_t)(nbase + r) * DIM + oo] = res;
}

extern "C" void kernel_launch(void* const* d_in, const int* in_sizes, int n_in,
                              void* d_out, int out_size, void* d_ws, size_t ws_size,
                              hipStream_t stream) {
    const float* x  = (const float*)d_in[0];
    const float* Wr = (const float*)d_in[1];
    const float* Wi = (const float*)d_in[2];
    const float* G  = (const float*)d_in[3];
    float* out = (float*)d_out;

    const size_t wq_bytes = (size_t)DIM * DIM * sizeof(float4);   // 256 KB
    const size_t wb_bytes = (size_t)DIM * DIM * sizeof(float2);   // 128 KB
    if (ws_size >= wq_bytes + wb_bytes) {
        float4* wq = (float4*)d_ws;
        float2* wb = (float2*)((char*)d_ws + wq_bytes);
        prep<<<(DIM * DIM + 255) / 256, 256, 0, stream>>>(Wr, Wi, G, wq, wb);
        // Diagnostics (garbage output, overwritten by final V0):
        main_kernel<4, 4><<<NROWS / RPB, NT, 0, stream>>>(x, wq, wb, out); // pure exec
        main_kernel<5, 4><<<NROWS / RPB, NT, 0, stream>>>(x, wq, wb, out); // pure mem+log
        main_kernel<7, 4><<<NROWS / RPB, NT, 0, stream>>>(x, wq, wb, out); // full, unrolled
        // Real kernel, last:
        main_kernel<0, 1><<<NROWS / RPB, NT, 0, stream>>>(x, wq, wb, out);
    } else {
        fb_kernel<<<NROWS / 8, NT, 0, stream>>>(x, Wr, Wi, G, out);
    }
}